// Round 4
// baseline (189623.572 us; speedup 1.0000x reference)
//
#include <hip/hip_runtime.h>
#include <hip/hip_fp16.h>
#include <stdint.h>
#include <string.h>

#define RES      8192
#define IN_DIM   64
#define DYN      1000
#define TOT      2000

#define BLOCKS   256         // 1 block/CU
#define TPB      512         // 8 waves/block -> VGPR budget 256/wave
#define ROWS_PB  32          // rows per block (4 per wave)
#define RPW      4           // rows per wave
#define DEPTH    8           // register-pipeline depth (of 16 iters)

// Output layout (floats):
//   prediction          [     0 ..  63999]
//   target              [ 64000 .. 127999]  copy of input[1000:2000]
//   prediction_augment  [128000 .. 255999]
//   target_augment      [256000 .. 383999]  copy of input
//
// ws layout (float indices). Sync lines padded to 128 B. ALL cross-block
// traffic uses relaxed agent-scope atomics (cache-bypass, coherence-point
// served) -> no fences, no L2 invalidates anywhere.  (Round-0 proven layout.)
#define WS_H0     0              // h buffer 0 [8192]
#define WS_H1     8192           // h buffer 1 [8192]
#define WS_OUT    16384          // outbuf [64]
#define WS_DONE   16448          // 64 producer-done slots x 32
#define WS_FLAG   18496          // 32 flag copies x 32
#define WS_GEN    19520          // 32 gen copies x 32
#define WS_SLOT   20544          // 512 arrival slots x 32 (256 used)
#define WS_TOTAL  36928          // floats to zero
#define WS_WH16   40960          // fp16 W_h starts here (float index; 16-B aligned)

__global__ void copy_targets(const float* __restrict__ input, float* __restrict__ out) {
    int i = blockIdx.x * blockDim.x + threadIdx.x;
    if (i < 64000)  out[64000 + i]  = input[64000 + i];   // target
    if (i < 128000) out[256000 + i] = input[i];           // target_augment
}

// fp32 -> fp16 conversion of W_h (67.1M elems). ~384 MiB of traffic, ~75 us.
__global__ void convert_wh(const float* __restrict__ W_h, __half2* __restrict__ w16) {
    const float4* src = (const float4*)W_h;
    const int stride = gridDim.x * blockDim.x;
    for (int j = blockIdx.x * blockDim.x + threadIdx.x;
         j < RES * RES / 4; j += stride) {
        float4 v = src[j];
        w16[2 * j]     = __floats2half2_rn(v.x, v.y);
        w16[2 * j + 1] = __floats2half2_rn(v.z, v.w);
    }
}

__device__ __forceinline__ unsigned ld_u32(const unsigned* p) {
    return __hip_atomic_load(p, __ATOMIC_RELAXED, __HIP_MEMORY_SCOPE_AGENT);
}
__device__ __forceinline__ void st_u32(unsigned* p, unsigned v) {
    __hip_atomic_store(p, v, __ATOMIC_RELAXED, __HIP_MEMORY_SCOPE_AGENT);
}
__device__ __forceinline__ float ld_f32(const float* p) {
    return __hip_atomic_load(p, __ATOMIC_RELAXED, __HIP_MEMORY_SCOPE_AGENT);
}
__device__ __forceinline__ void st_f32(float* p, float v) {
    __hip_atomic_store(p, v, __ATOMIC_RELAXED, __HIP_MEMORY_SCOPE_AGENT);
}
__device__ __forceinline__ void st_u64(uint64_t* p, uint64_t v) {
    __hip_atomic_store(p, v, __ATOMIC_RELAXED, __HIP_MEMORY_SCOPE_AGENT);
}
__device__ __forceinline__ uint64_t ld_u64(const uint64_t* p) {
    return __hip_atomic_load(p, __ATOMIC_RELAXED, __HIP_MEMORY_SCOPE_AGENT);
}
__device__ __forceinline__ float2 h2f2(unsigned u) {
    __half2 h;
    *reinterpret_cast<unsigned*>(&h) = u;
    return __half22float2(h);
}

template <bool FP16>
__global__ __launch_bounds__(TPB, 2) void esn_kernel(
    const float* __restrict__ input,   // 2000 x 64
    const float* __restrict__ W_in,    // 8192 x 64
    const float* __restrict__ W_h,     // 8192 x 8192 (fp32, used when !FP16)
    const float* __restrict__ W_out,   // 64 x 8192
    float* __restrict__ out,
    float* __restrict__ ws)
{
    __shared__ __align__(16) float h_lds[RES];
    __shared__ float xbuf[IN_DIM];

    float*    hbuf0  = ws + WS_H0;
    float*    hbuf1  = ws + WS_H1;
    float*    outbuf = ws + WS_OUT;
    unsigned* done   = (unsigned*)(ws + WS_DONE);
    unsigned* flag   = (unsigned*)(ws + WS_FLAG);
    unsigned* gen    = (unsigned*)(ws + WS_GEN);
    unsigned* slot   = (unsigned*)(ws + WS_SLOT);
    const __half2* wh16 = (const __half2*)(ws + WS_WH16);

    float* pred    = out;            // prediction
    float* aug_out = out + 128000;   // prediction_augment

    const int tid  = threadIdx.x;
    const int lane = tid & 63;
    const int wid  = tid >> 6;
    const int bid  = blockIdx.x;
    const int r0   = bid * ROWS_PB + wid * RPW;   // this wave's 4-row group

    // constant per-thread operands, hoisted out of the time loop
    const float w_in0 = W_in[(size_t)(r0 + 0) * IN_DIM + lane];
    const float w_in1 = W_in[(size_t)(r0 + 1) * IN_DIM + lane];
    const float w_in2 = W_in[(size_t)(r0 + 2) * IN_DIM + lane];
    const float w_in3 = W_in[(size_t)(r0 + 3) * IN_DIM + lane];

    const uint4* wp0 = (const uint4*)(wh16 + (size_t)(r0 + 0) * (RES / 2));
    const uint4* wp1 = (const uint4*)(wh16 + (size_t)(r0 + 1) * (RES / 2));
    const uint4* wp2 = (const uint4*)(wh16 + (size_t)(r0 + 2) * (RES / 2));
    const uint4* wp3 = (const uint4*)(wh16 + (size_t)(r0 + 3) * (RES / 2));

    for (int t = 0; t < TOT; ++t) {
        const float* hcur = (t & 1) ? hbuf1 : hbuf0;
        float*       hnxt = (t & 1) ? hbuf0 : hbuf1;

        // ---- stage h_t into LDS via cache-bypass loads (always-fresh) ----
        {
            const uint64_t* src = (const uint64_t*)hcur;
            uint64_t*       dst = (uint64_t*)h_lds;
            #pragma unroll
            for (int i = 0; i < RES / 2 / TPB; ++i)        // 8 iters
                dst[tid + i * TPB] = ld_u64(src + tid + i * TPB);
        }
        __syncthreads();

        // ---- producers: out_t[j] = W_out[j] @ aug(h_t), wave 1 of blocks 0..63 ----
        if (wid == 1 && bid < 64 && t >= 1) {
            const int j = bid;
            const float* wrow = W_out + (size_t)j * RES;
            float acc = 0.f;
            #pragma unroll 8
            for (int i = 0; i < RES / 256; ++i) {
                const int k = (lane << 2) + (i << 8);
                float4 w = *(const float4*)(wrow + k);
                float4 h = *(const float4*)(h_lds + k);
                // aug: even index -> h*h, odd -> h (k is a multiple of 4)
                acc += w.x * h.x * h.x + w.y * h.y + w.z * h.z * h.z + w.w * h.w;
            }
            #pragma unroll
            for (int off = 32; off; off >>= 1) acc += __shfl_xor(acc, off, 64);
            if (lane == 0) {
                if (t <= DYN)  aug_out[(size_t)(t - 1) * 64 + j] = acc;  // warm_up[t-1]
                if (t >= DYN) {
                    pred[(size_t)(t - DYN) * 64 + j] = acc;              // prediction
                    aug_out[(size_t)t * 64 + j]      = acc;              // aug[t]
                    st_f32(outbuf + j, acc);                             // fed back
                    __builtin_amdgcn_s_waitcnt(0);      // outbuf visible before done
                    st_u32(done + j * 32, (unsigned)(t - DYN + 1));
                }
            }
        }

        // ---- aggregator: wave 0 of block 64 collects done slots, fans flag out ----
        if (wid == 0 && bid == 64 && t >= DYN && t < TOT - 1) {
            const unsigned p = (unsigned)(t - DYN + 1);
            for (;;) {
                unsigned v = ld_u32(done + lane * 32);    // 64 distinct lines
                if (__all((int)(v >= p))) break;
                __builtin_amdgcn_s_sleep(2);
            }
            __builtin_amdgcn_s_waitcnt(0);
            if (lane < 32) st_u32(flag + lane * 32, p);
        }

        if (t == TOT - 1) break;   // last h-update is never consumed

        // ---- h_{t+1}[r0..r0+3] = tanh(W_in @ x_t + W_h @ h_t), 4 rows/wave,
        //      explicit uint4 loads + depth-8 register pipeline ----
        {
            float a00 = 0.f, a01 = 0.f, a02 = 0.f, a03 = 0.f;
            float a10 = 0.f, a11 = 0.f, a12 = 0.f, a13 = 0.f;
            float a20 = 0.f, a21 = 0.f, a22 = 0.f, a23 = 0.f;
            float a30 = 0.f, a31 = 0.f, a32 = 0.f, a33 = 0.f;
            if (FP16) {
                uint4 q0[DEPTH], q1[DEPTH], q2[DEPTH], q3[DEPTH];
                #pragma unroll
                for (int d = 0; d < DEPTH; ++d) {
                    const int idx = lane + 64 * d;
                    q0[d] = wp0[idx]; q1[d] = wp1[idx];
                    q2[d] = wp2[idx]; q3[d] = wp3[idx];
                }
                #pragma unroll
                for (int i = 0; i < 16; ++i) {             // fully unrolled
                    const int s = i & (DEPTH - 1);
                    const uint4 t0 = q0[s], t1 = q1[s], t2 = q2[s], t3 = q3[s];
                    if (i < 16 - DEPTH) {
                        const int idx = lane + 64 * (i + DEPTH);
                        q0[s] = wp0[idx]; q1[s] = wp1[idx];
                        q2[s] = wp2[idx]; q3[s] = wp3[idx];
                    }
                    const float4 hA = *(const float4*)(h_lds + 8 * lane + 512 * i);
                    const float4 hB = *(const float4*)(h_lds + 8 * lane + 512 * i + 4);
                    float2 f;
                    f = h2f2(t0.x); a00 += f.x * hA.x; a01 += f.y * hA.y;
                    f = h2f2(t0.y); a02 += f.x * hA.z; a03 += f.y * hA.w;
                    f = h2f2(t0.z); a00 += f.x * hB.x; a01 += f.y * hB.y;
                    f = h2f2(t0.w); a02 += f.x * hB.z; a03 += f.y * hB.w;
                    f = h2f2(t1.x); a10 += f.x * hA.x; a11 += f.y * hA.y;
                    f = h2f2(t1.y); a12 += f.x * hA.z; a13 += f.y * hA.w;
                    f = h2f2(t1.z); a10 += f.x * hB.x; a11 += f.y * hB.y;
                    f = h2f2(t1.w); a12 += f.x * hB.z; a13 += f.y * hB.w;
                    f = h2f2(t2.x); a20 += f.x * hA.x; a21 += f.y * hA.y;
                    f = h2f2(t2.y); a22 += f.x * hA.z; a23 += f.y * hA.w;
                    f = h2f2(t2.z); a20 += f.x * hB.x; a21 += f.y * hB.y;
                    f = h2f2(t2.w); a22 += f.x * hB.z; a23 += f.y * hB.w;
                    f = h2f2(t3.x); a30 += f.x * hA.x; a31 += f.y * hA.y;
                    f = h2f2(t3.y); a32 += f.x * hA.z; a33 += f.y * hA.w;
                    f = h2f2(t3.z); a30 += f.x * hB.x; a31 += f.y * hB.y;
                    f = h2f2(t3.w); a32 += f.x * hB.z; a33 += f.y * hB.w;
                }
            } else {
                const float* wrowA = W_h + (size_t)r0 * RES;
                #pragma unroll 4
                for (int i = 0; i < RES / 256; ++i) {
                    const int k = (lane << 2) + (i << 8);
                    float4 w0 = *(const float4*)(wrowA + k);
                    float4 w1 = *(const float4*)(wrowA + RES + k);
                    float4 w2 = *(const float4*)(wrowA + 2 * RES + k);
                    float4 w3 = *(const float4*)(wrowA + 3 * RES + k);
                    float4 h = *(const float4*)(h_lds + k);
                    a00 += w0.x * h.x; a01 += w0.y * h.y;
                    a02 += w0.z * h.z; a03 += w0.w * h.w;
                    a10 += w1.x * h.x; a11 += w1.y * h.y;
                    a12 += w1.z * h.z; a13 += w1.w * h.w;
                    a20 += w2.x * h.x; a21 += w2.y * h.y;
                    a22 += w2.z * h.z; a23 += w2.w * h.w;
                    a30 += w3.x * h.x; a31 += w3.y * h.y;
                    a32 += w3.z * h.z; a33 += w3.w * h.w;
                }
            }
            float acc0 = (a00 + a02) + (a01 + a03);
            float acc1 = (a10 + a12) + (a11 + a13);
            float acc2 = (a20 + a22) + (a21 + a23);
            float acc3 = (a30 + a32) + (a31 + a33);

            // x only needed now: warm -> input row; pred -> wait for flag
            // (overlapped with the whole W_h row-group load above), thread 0 polls.
            float x_l;
            if (t < DYN) {
                x_l = input[(size_t)t * IN_DIM + lane];
            } else {
                const unsigned p = (unsigned)(t - DYN + 1);
                __syncthreads();
                if (tid == 0) {
                    while (ld_u32(flag + (bid & 31) * 32) < p)
                        __builtin_amdgcn_s_sleep(2);
                }
                __syncthreads();
                if (tid < IN_DIM) xbuf[tid] = ld_f32(outbuf + tid);
                __syncthreads();
                x_l = xbuf[lane];
            }
            acc0 += w_in0 * x_l;
            acc1 += w_in1 * x_l;
            acc2 += w_in2 * x_l;
            acc3 += w_in3 * x_l;

            #pragma unroll
            for (int off = 32; off; off >>= 1) {
                acc0 += __shfl_xor(acc0, off, 64);
                acc1 += __shfl_xor(acc1, off, 64);
                acc2 += __shfl_xor(acc2, off, 64);
                acc3 += __shfl_xor(acc3, off, 64);
            }
            if (lane == 0) {
                float2 hv01, hv23;
                hv01.x = tanhf(acc0); hv01.y = tanhf(acc1);
                hv23.x = tanhf(acc2); hv23.y = tanhf(acc3);
                uint64_t u01, u23;
                memcpy(&u01, &hv01, 8);
                memcpy(&u23, &hv23, 8);
                st_u64((uint64_t*)(hnxt + r0), u01);       // r0 multiple of 4
                st_u64((uint64_t*)(hnxt + r0 + 2), u23);
            }
        }

        // ---- grid barrier: drain own stores, per-block slot store (no RMW),
        //      block 0 scans 256 distinct lines, fans gen out to 32 copies ----
        __builtin_amdgcn_s_waitcnt(0);
        __syncthreads();
        const unsigned e = (unsigned)(t + 1);
        if (tid == 0) st_u32(slot + bid * 32, e);
        if (bid == 0) {
            unsigned v = e;
            for (;;) {
                if (tid < BLOCKS) v = ld_u32(slot + tid * 32);
                if (__syncthreads_and(tid >= BLOCKS || v >= e)) break;
                __builtin_amdgcn_s_sleep(2);
            }
            if (tid < 32) st_u32(gen + tid * 32, e);
        } else {
            if (tid == 0) {
                while (ld_u32(gen + (bid & 31) * 32) < e)
                    __builtin_amdgcn_s_sleep(4);
            }
            __syncthreads();
        }
    }
}

extern "C" void kernel_launch(void* const* d_in, const int* in_sizes, int n_in,
                              void* d_out, int out_size, void* d_ws, size_t ws_size,
                              hipStream_t stream) {
    const float* input = (const float*)d_in[0];
    const float* W_in  = (const float*)d_in[1];
    const float* W_h   = (const float*)d_in[2];
    const float* W_out = (const float*)d_in[3];
    float* out = (float*)d_out;
    float* ws  = (float*)d_ws;

    // sync area + h buffers must start at zero (ws is poisoned 0xAA each call)
    hipMemsetAsync(d_ws, 0, WS_TOTAL * sizeof(float), stream);

    copy_targets<<<dim3((128000 + 255) / 256), dim3(256), 0, stream>>>(input, out);

    const size_t need = (size_t)WS_WH16 * sizeof(float)
                      + (size_t)RES * RES * sizeof(__half);
    if (ws_size >= need) {
        // fp16 W_h (128 MiB -> fully Infinity-Cache-resident)
        convert_wh<<<dim3(2048), dim3(1024), 0, stream>>>(
            W_h, (__half2*)(ws + WS_WH16));
        esn_kernel<true><<<dim3(BLOCKS), dim3(TPB), 0, stream>>>(
            input, W_in, W_h, W_out, out, ws);
    } else {
        // fallback: fp32 path
        esn_kernel<false><<<dim3(BLOCKS), dim3(TPB), 0, stream>>>(
            input, W_in, W_h, W_out, out, ws);
    }
}